// Round 1
// baseline (921.708 us; speedup 1.0000x reference)
//
#include <hip/hip_runtime.h>
#include <cstdint>
#include <cstddef>

#define N_TOK 4096
#define D_HID 2048
#define D_EXP 1024
#define NE 8
#define N_ROUTED (N_TOK * 2)
#define N_ROWS (N_ROUTED + N_TOK)   // 12288: 8192 routed slots + 4096 shared

typedef unsigned short u16;
typedef __bf16 bf16x8 __attribute__((ext_vector_type(8)));
typedef float f32x4 __attribute__((ext_vector_type(4)));

// ---------------- workspace layout (bytes) ----------------
constexpr size_t OFF_XB    = 0;                        // u16[N_TOK*D_HID]
constexpr size_t OFF_WG    = OFF_XB    + 16777216;     // u16[NE][D_EXP][D_HID]  (n,k)
constexpr size_t OFF_WU    = OFF_WG    + 33554432;     // u16[NE][D_EXP][D_HID]
constexpr size_t OFF_WD    = OFF_WU    + 33554432;     // u16[NE][D_HID][D_EXP]  (n,k)
constexpr size_t OFF_WSG   = OFF_WD    + 33554432;     // u16[D_EXP][D_HID]
constexpr size_t OFF_WSU   = OFF_WSG   + 4194304;      // u16[D_EXP][D_HID]
constexpr size_t OFF_WSD   = OFF_WSU   + 4194304;      // u16[D_HID][D_EXP]
constexpr size_t OFF_H     = OFF_WSD   + 4194304;      // u16[N_ROWS*D_EXP]
constexpr size_t OFF_ROWS  = OFF_H     + 25165824;     // int[N_ROWS]
constexpr size_t OFF_WSLOT = OFF_ROWS  + 49152;        // float[N_ROWS]
constexpr size_t OFF_SEG   = OFF_WSLOT + 49152;        // int[32]: start[0..8] at 0.., len[0..8] at 16..
constexpr size_t OFF_TOPI  = OFF_SEG   + 256;          // int[2*N_TOK]
constexpr size_t OFF_TOPW  = OFF_TOPI  + 32768;        // float[2*N_TOK]

__device__ __forceinline__ u16 f32_to_bf16(float f) {
    union { float f; unsigned int u; } c; c.f = f;
    unsigned int u = c.u;
    return (u16)((u + 0x7FFFu + ((u >> 16) & 1u)) >> 16);
}

// ---------------- zero d_out ----------------
__global__ void zero_out_kernel(float* __restrict__ out) {
    size_t i = ((size_t)blockIdx.x * 256 + threadIdx.x) * 4;
    float4 z = make_float4(0.f, 0.f, 0.f, 0.f);
    *(float4*)(out + i) = z;
}

// ---------------- x -> bf16 ----------------
__global__ void cvt_x_kernel(const float* __restrict__ x, u16* __restrict__ xb) {
    size_t i = ((size_t)blockIdx.x * 256 + threadIdx.x) * 8;
    float4 a = *(const float4*)(x + i);
    float4 b = *(const float4*)(x + i + 4);
    union { u16 us[8]; uint4 v; } r;
    r.us[0] = f32_to_bf16(a.x); r.us[1] = f32_to_bf16(a.y);
    r.us[2] = f32_to_bf16(a.z); r.us[3] = f32_to_bf16(a.w);
    r.us[4] = f32_to_bf16(b.x); r.us[5] = f32_to_bf16(b.y);
    r.us[6] = f32_to_bf16(b.z); r.us[7] = f32_to_bf16(b.w);
    *(uint4*)(xb + i) = r.v;
}

// ---------------- fp32 [R][C] -> bf16 [C][R] (per batch z) ----------------
__global__ void transpose_cvt_kernel(const float* __restrict__ src, u16* __restrict__ dst,
                                     int R, int C) {
    __shared__ float tile[32][33];
    const int tx = threadIdx.x, ty = threadIdx.y;         // 32 x 8
    const size_t m = (size_t)blockIdx.z * R * C;
    const int c0 = blockIdx.x * 32, r0 = blockIdx.y * 32;
#pragma unroll
    for (int i = 0; i < 4; i++)
        tile[ty + 8 * i][tx] = src[m + (size_t)(r0 + ty + 8 * i) * C + c0 + tx];
    __syncthreads();
#pragma unroll
    for (int i = 0; i < 4; i++)
        dst[m + (size_t)(c0 + ty + 8 * i) * R + r0 + tx] = f32_to_bf16(tile[tx][ty + 8 * i]);
}

// ---------------- router: softmax + top2 ----------------
__global__ void router_kernel(const float* __restrict__ x, const float* __restrict__ Wg,
                              int* __restrict__ topi, float* __restrict__ topw) {
    const int wave = threadIdx.x >> 6, lane = threadIdx.x & 63;
    const int t = blockIdx.x * 4 + wave;
    const float* xr = x + (size_t)t * D_HID;
    float acc[8] = {0.f, 0.f, 0.f, 0.f, 0.f, 0.f, 0.f, 0.f};
    for (int k = lane; k < D_HID; k += 64) {
        float xv = xr[k];
        float4 w0 = *(const float4*)(Wg + k * 8);
        float4 w1 = *(const float4*)(Wg + k * 8 + 4);
        acc[0] += xv * w0.x; acc[1] += xv * w0.y; acc[2] += xv * w0.z; acc[3] += xv * w0.w;
        acc[4] += xv * w1.x; acc[5] += xv * w1.y; acc[6] += xv * w1.z; acc[7] += xv * w1.w;
    }
#pragma unroll
    for (int e = 0; e < 8; e++)
#pragma unroll
        for (int off = 32; off > 0; off >>= 1)
            acc[e] += __shfl_xor(acc[e], off);
    if (lane == 0) {
        float mx = acc[0];
#pragma unroll
        for (int e = 1; e < 8; e++) mx = fmaxf(mx, acc[e]);
        float p[8], sum = 0.f;
#pragma unroll
        for (int e = 0; e < 8; e++) { p[e] = __expf(acc[e] - mx); sum += p[e]; }
        int i0 = 0; float b0 = p[0];
#pragma unroll
        for (int e = 1; e < 8; e++) if (p[e] > b0) { b0 = p[e]; i0 = e; }
        int i1 = -1; float b1 = -1.f;
#pragma unroll
        for (int e = 0; e < 8; e++) if (e != i0 && p[e] > b1) { b1 = p[e]; i1 = e; }
        float inv = 1.f / sum;
        topi[t * 2] = i0;  topi[t * 2 + 1] = i1;
        topw[t * 2] = b0 * inv; topw[t * 2 + 1] = b1 * inv;
    }
}

// ---------------- build expert segments (single block) ----------------
__global__ void builder_kernel(const int* __restrict__ topi, const float* __restrict__ topw,
                               int* __restrict__ rows, float* __restrict__ wslot,
                               int* __restrict__ seg) {
    __shared__ int cnt[8], offs[8];
    const int tid = threadIdx.x;
    if (tid < 8) cnt[tid] = 0;
    __syncthreads();
    for (int i = tid; i < N_TOK * 2; i += 256) atomicAdd(&cnt[topi[i]], 1);
    __syncthreads();
    if (tid == 0) {
        int run = 0;
        for (int e = 0; e < 8; e++) {
            offs[e] = run; seg[e] = run; seg[16 + e] = cnt[e]; run += cnt[e];
        }
        seg[8] = N_ROUTED; seg[16 + 8] = N_TOK;
    }
    __syncthreads();
    for (int i = tid; i < N_TOK * 2; i += 256) {
        int e = topi[i];
        int p = atomicAdd(&offs[e], 1);
        rows[p] = i >> 1;
        wslot[p] = topw[i];
    }
    for (int t = tid; t < N_TOK; t += 256) {
        rows[N_ROUTED + t] = t;
        wslot[N_ROUTED + t] = 1.0f;
    }
}

// ---------------- GEMM1: gathered X @ {W_gate, W_up} + silu*up*w -> h (bf16) ----------------
__global__ __launch_bounds__(256, 2)
void gemm1_kernel(const u16* __restrict__ xb,
                  const u16* __restrict__ Wg_t, const u16* __restrict__ Wu_t,
                  const u16* __restrict__ Wsg_t, const u16* __restrict__ Wsu_t,
                  const int* __restrict__ rows, const float* __restrict__ wslot,
                  const int* __restrict__ seg, u16* __restrict__ h) {
    const int e = blockIdx.x >> 5;
    const int rb = blockIdx.x & 31;
    const int s = seg[e], L = seg[e + 16];
    if (rb * 128 >= L) return;
    const u16* Bg = (e < NE) ? Wg_t + (size_t)e * D_EXP * D_HID : Wsg_t;
    const u16* Bu = (e < NE) ? Wu_t + (size_t)e * D_EXP * D_HID : Wsu_t;
    const int cbase = blockIdx.y * 128;

    __shared__ u16 As[128 * 32];
    __shared__ u16 Bgs[128 * 32];
    __shared__ u16 Bus[128 * 32];
    __shared__ int tok_s[128];

    const int tid = threadIdx.x;
    if (tid < 128) {
        int lr = rb * 128 + tid;
        tok_s[tid] = rows[s + (lr < L ? lr : 0)];
    }
    __syncthreads();
    const int r0 = tid >> 2, q = tid & 3;
    const size_t tokoff0 = (size_t)tok_s[r0] * D_HID;
    const size_t tokoff1 = (size_t)tok_s[r0 + 64] * D_HID;

    const int lane = tid & 63, wave = tid >> 6;
    const int wm = wave & 1, wn = wave >> 1;
    const int ln = lane & 15, quad = lane >> 4;

    f32x4 accg[4][4], accu[4][4];
    const f32x4 zero = {0.f, 0.f, 0.f, 0.f};
#pragma unroll
    for (int i = 0; i < 4; i++)
#pragma unroll
        for (int j = 0; j < 4; j++) { accg[i][j] = zero; accu[i][j] = zero; }

    for (int k0 = 0; k0 < D_HID; k0 += 32) {
        const uint4 a0  = *(const uint4*)(xb + tokoff0 + k0 + q * 8);
        const uint4 a1  = *(const uint4*)(xb + tokoff1 + k0 + q * 8);
        const uint4 bg0 = *(const uint4*)(Bg + (size_t)(cbase + r0) * D_HID + k0 + q * 8);
        const uint4 bg1 = *(const uint4*)(Bg + (size_t)(cbase + r0 + 64) * D_HID + k0 + q * 8);
        const uint4 bu0 = *(const uint4*)(Bu + (size_t)(cbase + r0) * D_HID + k0 + q * 8);
        const uint4 bu1 = *(const uint4*)(Bu + (size_t)(cbase + r0 + 64) * D_HID + k0 + q * 8);
        __syncthreads();
        *(uint4*)&As[r0 * 32 + q * 8] = a0;
        *(uint4*)&As[(r0 + 64) * 32 + q * 8] = a1;
        *(uint4*)&Bgs[r0 * 32 + q * 8] = bg0;
        *(uint4*)&Bgs[(r0 + 64) * 32 + q * 8] = bg1;
        *(uint4*)&Bus[r0 * 32 + q * 8] = bu0;
        *(uint4*)&Bus[(r0 + 64) * 32 + q * 8] = bu1;
        __syncthreads();
        bf16x8 af[4];
#pragma unroll
        for (int sm = 0; sm < 4; sm++)
            af[sm] = *(const bf16x8*)&As[(wm * 64 + sm * 16 + ln) * 32 + quad * 8];
#pragma unroll
        for (int sn = 0; sn < 4; sn++) {
            const bf16x8 bgf = *(const bf16x8*)&Bgs[(wn * 64 + sn * 16 + ln) * 32 + quad * 8];
            const bf16x8 buf = *(const bf16x8*)&Bus[(wn * 64 + sn * 16 + ln) * 32 + quad * 8];
#pragma unroll
            for (int sm = 0; sm < 4; sm++) {
                accg[sm][sn] = __builtin_amdgcn_mfma_f32_16x16x32_bf16(af[sm], bgf, accg[sm][sn], 0, 0, 0);
                accu[sm][sn] = __builtin_amdgcn_mfma_f32_16x16x32_bf16(af[sm], buf, accu[sm][sn], 0, 0, 0);
            }
        }
    }
    // epilogue: h = silu(g) * u * w    (C/D: col=lane&15, row=quad*4+reg)
#pragma unroll
    for (int sm = 0; sm < 4; sm++) {
#pragma unroll
        for (int r = 0; r < 4; r++) {
            int lrow = rb * 128 + wm * 64 + sm * 16 + quad * 4 + r;
            if (lrow >= L) continue;
            int pos = s + lrow;
            float w = wslot[pos];
#pragma unroll
            for (int sn = 0; sn < 4; sn++) {
                float g = accg[sm][sn][r];
                float u = accu[sm][sn][r];
                float hv = (g / (1.f + __expf(-g))) * u * w;
                int col = cbase + wn * 64 + sn * 16 + ln;
                h[(size_t)pos * D_EXP + col] = f32_to_bf16(hv);
            }
        }
    }
}

// ---------------- GEMM2: h @ W_down, scatter-add into out ----------------
__global__ __launch_bounds__(256, 2)
void gemm2_kernel(const u16* __restrict__ h,
                  const u16* __restrict__ Wd_t, const u16* __restrict__ Wsd_t,
                  const int* __restrict__ rows, const int* __restrict__ seg,
                  float* __restrict__ out) {
    const int e = blockIdx.x >> 5;
    const int rb = blockIdx.x & 31;
    const int s = seg[e], L = seg[e + 16];
    if (rb * 128 >= L) return;
    const u16* B = (e < NE) ? Wd_t + (size_t)e * D_HID * D_EXP : Wsd_t;  // [N=2048][K=1024]
    const int cbase = blockIdx.y * 128;

    __shared__ u16 As[128 * 32];
    __shared__ u16 Bs[128 * 32];

    const int tid = threadIdx.x;
    const int r0 = tid >> 2, q = tid & 3;
    const int lane = tid & 63, wave = tid >> 6;
    const int wm = wave & 1, wn = wave >> 1;
    const int ln = lane & 15, quad = lane >> 4;

    f32x4 acc[4][4];
    const f32x4 zero = {0.f, 0.f, 0.f, 0.f};
#pragma unroll
    for (int i = 0; i < 4; i++)
#pragma unroll
        for (int j = 0; j < 4; j++) acc[i][j] = zero;

    const size_t arow0 = (size_t)(s + rb * 128 + r0) * D_EXP;
    const size_t arow1 = arow0 + (size_t)64 * D_EXP;

    for (int k0 = 0; k0 < D_EXP; k0 += 32) {
        const uint4 a0 = *(const uint4*)(h + arow0 + k0 + q * 8);
        const uint4 a1 = *(const uint4*)(h + arow1 + k0 + q * 8);
        const uint4 b0 = *(const uint4*)(B + (size_t)(cbase + r0) * D_EXP + k0 + q * 8);
        const uint4 b1 = *(const uint4*)(B + (size_t)(cbase + r0 + 64) * D_EXP + k0 + q * 8);
        __syncthreads();
        *(uint4*)&As[r0 * 32 + q * 8] = a0;
        *(uint4*)&As[(r0 + 64) * 32 + q * 8] = a1;
        *(uint4*)&Bs[r0 * 32 + q * 8] = b0;
        *(uint4*)&Bs[(r0 + 64) * 32 + q * 8] = b1;
        __syncthreads();
        bf16x8 af[4];
#pragma unroll
        for (int sm = 0; sm < 4; sm++)
            af[sm] = *(const bf16x8*)&As[(wm * 64 + sm * 16 + ln) * 32 + quad * 8];
#pragma unroll
        for (int sn = 0; sn < 4; sn++) {
            const bf16x8 bfg = *(const bf16x8*)&Bs[(wn * 64 + sn * 16 + ln) * 32 + quad * 8];
#pragma unroll
            for (int sm = 0; sm < 4; sm++)
                acc[sm][sn] = __builtin_amdgcn_mfma_f32_16x16x32_bf16(af[sm], bfg, acc[sm][sn], 0, 0, 0);
        }
    }
#pragma unroll
    for (int sm = 0; sm < 4; sm++) {
#pragma unroll
        for (int r = 0; r < 4; r++) {
            int lrow = rb * 128 + wm * 64 + sm * 16 + quad * 4 + r;
            if (lrow >= L) continue;
            int tok = rows[s + lrow];
#pragma unroll
            for (int sn = 0; sn < 4; sn++) {
                int col = cbase + wn * 64 + sn * 16 + ln;
                atomicAdd(out + (size_t)tok * D_HID + col, acc[sm][sn][r]);
            }
        }
    }
}

// ---------------- launch ----------------
extern "C" void kernel_launch(void* const* d_in, const int* in_sizes, int n_in,
                              void* d_out, int out_size, void* d_ws, size_t ws_size,
                              hipStream_t stream) {
    const float* x       = (const float*)d_in[0];
    const float* W_g     = (const float*)d_in[1];
    const float* W_gate  = (const float*)d_in[2];
    const float* W_up    = (const float*)d_in[3];
    const float* W_down  = (const float*)d_in[4];
    const float* Ws_gate = (const float*)d_in[5];
    const float* Ws_up   = (const float*)d_in[6];
    const float* Ws_down = (const float*)d_in[7];
    float* out = (float*)d_out;
    char* ws = (char*)d_ws;

    u16*   xb    = (u16*)(ws + OFF_XB);
    u16*   Wg_t  = (u16*)(ws + OFF_WG);
    u16*   Wu_t  = (u16*)(ws + OFF_WU);
    u16*   Wd_t  = (u16*)(ws + OFF_WD);
    u16*   Wsg_t = (u16*)(ws + OFF_WSG);
    u16*   Wsu_t = (u16*)(ws + OFF_WSU);
    u16*   Wsd_t = (u16*)(ws + OFF_WSD);
    u16*   h     = (u16*)(ws + OFF_H);
    int*   rows  = (int*)(ws + OFF_ROWS);
    float* wslot = (float*)(ws + OFF_WSLOT);
    int*   seg   = (int*)(ws + OFF_SEG);
    int*   topi  = (int*)(ws + OFF_TOPI);
    float* topw  = (float*)(ws + OFF_TOPW);

    zero_out_kernel<<<dim3((N_TOK * D_HID) / (256 * 4)), dim3(256), 0, stream>>>(out);
    cvt_x_kernel<<<dim3((N_TOK * D_HID) / (256 * 8)), dim3(256), 0, stream>>>(x, xb);

    dim3 tb(32, 8);
    transpose_cvt_kernel<<<dim3(D_EXP / 32, D_HID / 32, NE), tb, 0, stream>>>(W_gate, Wg_t, D_HID, D_EXP);
    transpose_cvt_kernel<<<dim3(D_EXP / 32, D_HID / 32, NE), tb, 0, stream>>>(W_up, Wu_t, D_HID, D_EXP);
    transpose_cvt_kernel<<<dim3(D_HID / 32, D_EXP / 32, NE), tb, 0, stream>>>(W_down, Wd_t, D_EXP, D_HID);
    transpose_cvt_kernel<<<dim3(D_EXP / 32, D_HID / 32, 1), tb, 0, stream>>>(Ws_gate, Wsg_t, D_HID, D_EXP);
    transpose_cvt_kernel<<<dim3(D_EXP / 32, D_HID / 32, 1), tb, 0, stream>>>(Ws_up, Wsu_t, D_HID, D_EXP);
    transpose_cvt_kernel<<<dim3(D_HID / 32, D_EXP / 32, 1), tb, 0, stream>>>(Ws_down, Wsd_t, D_EXP, D_HID);

    router_kernel<<<dim3(N_TOK / 4), dim3(256), 0, stream>>>(x, W_g, topi, topw);
    builder_kernel<<<dim3(1), dim3(256), 0, stream>>>(topi, topw, rows, wslot, seg);

    gemm1_kernel<<<dim3(9 * 32, D_EXP / 128), dim3(256), 0, stream>>>(
        xb, Wg_t, Wu_t, Wsg_t, Wsu_t, rows, wslot, seg, h);
    gemm2_kernel<<<dim3(9 * 32, D_HID / 128), dim3(256), 0, stream>>>(
        h, Wd_t, Wsd_t, rows, seg, out);
}

// Round 2
// 623.593 us; speedup vs baseline: 1.4781x; 1.4781x over previous
//
#include <hip/hip_runtime.h>
#include <cstdint>
#include <cstddef>

#define N_TOK 4096
#define D_HID 2048
#define D_EXP 1024
#define NE 8
#define N_ROUTED (N_TOK * 2)
#define N_ROWS (N_ROUTED + N_TOK)   // 12288: 8192 routed slots + 4096 shared
#define MAX_BLK 112                 // >= worst-case row-blocks (103)

typedef unsigned short u16;
typedef __bf16 bf16x8 __attribute__((ext_vector_type(8)));
typedef float f32x4 __attribute__((ext_vector_type(4)));

// ---------------- workspace layout (bytes) ----------------
constexpr size_t OFF_XB    = 0;                        // u16[N_TOK*D_HID]
constexpr size_t OFF_WG    = OFF_XB    + 16777216;     // u16[NE][D_EXP][D_HID]  (n,k)
constexpr size_t OFF_WU    = OFF_WG    + 33554432;     // u16[NE][D_EXP][D_HID]
constexpr size_t OFF_WD    = OFF_WU    + 33554432;     // u16[NE][D_HID][D_EXP]  (n,k)
constexpr size_t OFF_WSG   = OFF_WD    + 33554432;     // u16[D_EXP][D_HID]
constexpr size_t OFF_WSU   = OFF_WSG   + 4194304;      // u16[D_EXP][D_HID]
constexpr size_t OFF_WSD   = OFF_WSU   + 4194304;      // u16[D_HID][D_EXP]
constexpr size_t OFF_H     = OFF_WSD   + 4194304;      // u16[N_ROWS*D_EXP]
constexpr size_t OFF_ROWS  = OFF_H     + 25165824;     // int[N_ROWS]
constexpr size_t OFF_WSLOT = OFF_ROWS  + 49152;        // float[N_ROWS]
constexpr size_t OFF_SEG   = OFF_WSLOT + 49152;        // int[32]: start[0..8], len[16..24], nblk[10]
constexpr size_t OFF_BLK   = OFF_SEG   + 128;          // int[160] block map
constexpr size_t OFF_TOPI  = OFF_BLK   + 768;          // int[2*N_TOK]
constexpr size_t OFF_TOPW  = OFF_TOPI  + 32768;        // float[2*N_TOK]

__device__ __forceinline__ u16 f32_to_bf16(float f) {
    union { float f; unsigned int u; } c; c.f = f;
    unsigned int u = c.u;
    return (u16)((u + 0x7FFFu + ((u >> 16) & 1u)) >> 16);
}

// async global->LDS, 16B per lane; lds dest = wave-uniform base + lane*16
__device__ __forceinline__ void gld_lds16(const u16* g, u16* l) {
    __builtin_amdgcn_global_load_lds(
        (const __attribute__((address_space(1))) void*)g,
        (__attribute__((address_space(3))) void*)l,
        16, 0, 0);
}

// ---------------- zero d_out ----------------
__global__ void zero_out_kernel(float* __restrict__ out) {
    size_t i = ((size_t)blockIdx.x * 256 + threadIdx.x) * 4;
    float4 z = make_float4(0.f, 0.f, 0.f, 0.f);
    *(float4*)(out + i) = z;
}

// ---------------- x -> bf16 ----------------
__global__ void cvt_x_kernel(const float* __restrict__ x, u16* __restrict__ xb) {
    size_t i = ((size_t)blockIdx.x * 256 + threadIdx.x) * 8;
    float4 a = *(const float4*)(x + i);
    float4 b = *(const float4*)(x + i + 4);
    union { u16 us[8]; uint4 v; } r;
    r.us[0] = f32_to_bf16(a.x); r.us[1] = f32_to_bf16(a.y);
    r.us[2] = f32_to_bf16(a.z); r.us[3] = f32_to_bf16(a.w);
    r.us[4] = f32_to_bf16(b.x); r.us[5] = f32_to_bf16(b.y);
    r.us[6] = f32_to_bf16(b.z); r.us[7] = f32_to_bf16(b.w);
    *(uint4*)(xb + i) = r.v;
}

// ---------------- fp32 [R][C] -> bf16 [C][R] (per batch z) ----------------
__global__ void transpose_cvt_kernel(const float* __restrict__ src, u16* __restrict__ dst,
                                     int R, int C) {
    __shared__ float tile[32][33];
    const int tx = threadIdx.x, ty = threadIdx.y;         // 32 x 8
    const size_t m = (size_t)blockIdx.z * R * C;
    const int c0 = blockIdx.x * 32, r0 = blockIdx.y * 32;
#pragma unroll
    for (int i = 0; i < 4; i++)
        tile[ty + 8 * i][tx] = src[m + (size_t)(r0 + ty + 8 * i) * C + c0 + tx];
    __syncthreads();
#pragma unroll
    for (int i = 0; i < 4; i++)
        dst[m + (size_t)(c0 + ty + 8 * i) * R + r0 + tx] = f32_to_bf16(tile[tx][ty + 8 * i]);
}

// ---------------- router: softmax + top2 ----------------
__global__ void router_kernel(const float* __restrict__ x, const float* __restrict__ Wg,
                              int* __restrict__ topi, float* __restrict__ topw) {
    const int wave = threadIdx.x >> 6, lane = threadIdx.x & 63;
    const int t = blockIdx.x * 4 + wave;
    const float* xr = x + (size_t)t * D_HID;
    float acc[8] = {0.f, 0.f, 0.f, 0.f, 0.f, 0.f, 0.f, 0.f};
    for (int k = lane; k < D_HID; k += 64) {
        float xv = xr[k];
        float4 w0 = *(const float4*)(Wg + k * 8);
        float4 w1 = *(const float4*)(Wg + k * 8 + 4);
        acc[0] += xv * w0.x; acc[1] += xv * w0.y; acc[2] += xv * w0.z; acc[3] += xv * w0.w;
        acc[4] += xv * w1.x; acc[5] += xv * w1.y; acc[6] += xv * w1.z; acc[7] += xv * w1.w;
    }
#pragma unroll
    for (int e = 0; e < 8; e++)
#pragma unroll
        for (int off = 32; off > 0; off >>= 1)
            acc[e] += __shfl_xor(acc[e], off);
    if (lane == 0) {
        float mx = acc[0];
#pragma unroll
        for (int e = 1; e < 8; e++) mx = fmaxf(mx, acc[e]);
        float p[8], sum = 0.f;
#pragma unroll
        for (int e = 0; e < 8; e++) { p[e] = __expf(acc[e] - mx); sum += p[e]; }
        int i0 = 0; float b0 = p[0];
#pragma unroll
        for (int e = 1; e < 8; e++) if (p[e] > b0) { b0 = p[e]; i0 = e; }
        int i1 = -1; float b1 = -1.f;
#pragma unroll
        for (int e = 0; e < 8; e++) if (e != i0 && p[e] > b1) { b1 = p[e]; i1 = e; }
        float inv = 1.f / sum;
        topi[t * 2] = i0;  topi[t * 2 + 1] = i1;
        topw[t * 2] = b0 * inv; topw[t * 2 + 1] = b1 * inv;
    }
}

// ---------------- build expert segments + block map (single block) ----------------
__global__ void builder_kernel(const int* __restrict__ topi, const float* __restrict__ topw,
                               int* __restrict__ rows, float* __restrict__ wslot,
                               int* __restrict__ seg, int* __restrict__ blkmap) {
    __shared__ int cnt[8], offs[8];
    const int tid = threadIdx.x;
    if (tid < 8) cnt[tid] = 0;
    __syncthreads();
    for (int i = tid; i < N_TOK * 2; i += 256) atomicAdd(&cnt[topi[i]], 1);
    __syncthreads();
    if (tid == 0) {
        int run = 0;
        for (int e = 0; e < 8; e++) {
            offs[e] = run; seg[e] = run; seg[16 + e] = cnt[e]; run += cnt[e];
        }
        seg[8] = N_ROUTED; seg[16 + 8] = N_TOK;
        // packed (expert, row-block) map
        int nb = 0;
        for (int e = 0; e < 9; e++) {
            int L = (e < 8) ? cnt[e] : N_TOK;
            for (int rb = 0; rb * 128 < L; rb++) blkmap[nb++] = (e << 8) | rb;
        }
        seg[10] = nb;
    }
    __syncthreads();
    for (int i = tid; i < N_TOK * 2; i += 256) {
        int e = topi[i];
        int p = atomicAdd(&offs[e], 1);
        rows[p] = i >> 1;
        wslot[p] = topw[i];
    }
    for (int t = tid; t < N_TOK; t += 256) {
        rows[N_ROUTED + t] = t;
        wslot[N_ROUTED + t] = 1.0f;
    }
}

// ---------------- GEMM1: gathered X @ {W_gate, W_up} + silu*up*w -> h (bf16) ----------------
__global__ __launch_bounds__(256, 2)
void gemm1_kernel(const u16* __restrict__ xb,
                  const u16* __restrict__ Wg_t, const u16* __restrict__ Wu_t,
                  const u16* __restrict__ Wsg_t, const u16* __restrict__ Wsu_t,
                  const int* __restrict__ rows, const float* __restrict__ wslot,
                  const int* __restrict__ seg, const int* __restrict__ blkmap,
                  u16* __restrict__ h) {
    if ((int)blockIdx.x >= seg[10]) return;
    const int code = blkmap[blockIdx.x];
    const int e = code >> 8, rb = code & 255;
    const int s = seg[e], L = seg[e + 16];
    const u16* Bg = (e < NE) ? Wg_t + (size_t)e * D_EXP * D_HID : Wsg_t;
    const u16* Bu = (e < NE) ? Wu_t + (size_t)e * D_EXP * D_HID : Wsu_t;
    const int cbase = blockIdx.y * 128;

    __shared__ u16 As[128 * 32];
    __shared__ u16 Bgs[128 * 32];
    __shared__ u16 Bus[128 * 32];
    __shared__ int tok_s[128];

    const int tid = threadIdx.x;
    if (tid < 128) {
        int lr = rb * 128 + tid;
        tok_s[tid] = rows[s + (lr < L ? lr : 0)];
    }
    __syncthreads();

    const int lane = tid & 63, wave = tid >> 6;
    const int wm = wave & 1, wn = wave >> 1;
    const int ln = lane & 15, quad = lane >> 4;

    // staging geometry: wave covers tile rows [wave*32, wave*32+32), 2 instrs per tile
    const int lr16 = lane >> 2;                 // 0..15 row within 16-row chunk
    const int c8 = (lane & 3) * 8;              // element col within 32-wide K-slab
    const int ra0 = wave * 32 + lr16, ra1 = ra0 + 16;
    const size_t ta0 = (size_t)tok_s[ra0] * D_HID + c8;
    const size_t ta1 = (size_t)tok_s[ra1] * D_HID + c8;
    const u16* pbg0 = Bg + (size_t)(cbase + ra0) * D_HID + c8;
    const u16* pbg1 = Bg + (size_t)(cbase + ra1) * D_HID + c8;
    const u16* pbu0 = Bu + (size_t)(cbase + ra0) * D_HID + c8;
    const u16* pbu1 = Bu + (size_t)(cbase + ra1) * D_HID + c8;
    u16* lA0 = As + (size_t)(wave * 32) * 32;
    u16* lA1 = As + (size_t)(wave * 32 + 16) * 32;
    u16* lG0 = Bgs + (size_t)(wave * 32) * 32;
    u16* lG1 = Bgs + (size_t)(wave * 32 + 16) * 32;
    u16* lU0 = Bus + (size_t)(wave * 32) * 32;
    u16* lU1 = Bus + (size_t)(wave * 32 + 16) * 32;

    f32x4 accg[4][4], accu[4][4];
    const f32x4 zero = {0.f, 0.f, 0.f, 0.f};
#pragma unroll
    for (int i = 0; i < 4; i++)
#pragma unroll
        for (int j = 0; j < 4; j++) { accg[i][j] = zero; accu[i][j] = zero; }

    for (int k0 = 0; k0 < D_HID; k0 += 32) {
        __syncthreads();   // all waves done reading previous tile
        gld_lds16(xb + ta0 + k0, lA0);
        gld_lds16(xb + ta1 + k0, lA1);
        gld_lds16(pbg0 + k0, lG0);
        gld_lds16(pbg1 + k0, lG1);
        gld_lds16(pbu0 + k0, lU0);
        gld_lds16(pbu1 + k0, lU1);
        __syncthreads();   // vmcnt drain -> tile visible
        bf16x8 af[4];
#pragma unroll
        for (int sm = 0; sm < 4; sm++)
            af[sm] = *(const bf16x8*)&As[(wm * 64 + sm * 16 + ln) * 32 + quad * 8];
#pragma unroll
        for (int sn = 0; sn < 4; sn++) {
            const bf16x8 bgf = *(const bf16x8*)&Bgs[(wn * 64 + sn * 16 + ln) * 32 + quad * 8];
            const bf16x8 buf = *(const bf16x8*)&Bus[(wn * 64 + sn * 16 + ln) * 32 + quad * 8];
#pragma unroll
            for (int sm = 0; sm < 4; sm++) {
                accg[sm][sn] = __builtin_amdgcn_mfma_f32_16x16x32_bf16(af[sm], bgf, accg[sm][sn], 0, 0, 0);
                accu[sm][sn] = __builtin_amdgcn_mfma_f32_16x16x32_bf16(af[sm], buf, accu[sm][sn], 0, 0, 0);
            }
        }
    }
    // epilogue: h = silu(g) * u * w    (C/D: col=lane&15, row=quad*4+reg)
#pragma unroll
    for (int sm = 0; sm < 4; sm++) {
#pragma unroll
        for (int r = 0; r < 4; r++) {
            int lrow = rb * 128 + wm * 64 + sm * 16 + quad * 4 + r;
            if (lrow >= L) continue;
            int pos = s + lrow;
            float w = wslot[pos];
#pragma unroll
            for (int sn = 0; sn < 4; sn++) {
                float g = accg[sm][sn][r];
                float u = accu[sm][sn][r];
                float hv = (g / (1.f + __expf(-g))) * u * w;
                int col = cbase + wn * 64 + sn * 16 + ln;
                h[(size_t)pos * D_EXP + col] = f32_to_bf16(hv);
            }
        }
    }
}

// ---------------- GEMM2: h @ W_down, scatter-add into out ----------------
__global__ __launch_bounds__(256, 2)
void gemm2_kernel(const u16* __restrict__ h,
                  const u16* __restrict__ Wd_t, const u16* __restrict__ Wsd_t,
                  const int* __restrict__ rows, const int* __restrict__ seg,
                  const int* __restrict__ blkmap, float* __restrict__ out) {
    if ((int)blockIdx.x >= seg[10]) return;
    const int code = blkmap[blockIdx.x];
    const int e = code >> 8, rb = code & 255;
    const int s = seg[e], L = seg[e + 16];
    const u16* B = (e < NE) ? Wd_t + (size_t)e * D_HID * D_EXP : Wsd_t;  // [N=2048][K=1024]
    const int cbase = blockIdx.y * 128;

    __shared__ u16 As[128 * 32];
    __shared__ u16 Bs[128 * 32];

    const int tid = threadIdx.x;
    const int lane = tid & 63, wave = tid >> 6;
    const int wm = wave & 1, wn = wave >> 1;
    const int ln = lane & 15, quad = lane >> 4;

    const int lr16 = lane >> 2;
    const int c8 = (lane & 3) * 8;
    const int ra0 = wave * 32 + lr16, ra1 = ra0 + 16;
    const u16* pa0 = h + (size_t)(s + rb * 128 + ra0) * D_EXP + c8;
    const u16* pa1 = h + (size_t)(s + rb * 128 + ra1) * D_EXP + c8;
    const u16* pb0 = B + (size_t)(cbase + ra0) * D_EXP + c8;
    const u16* pb1 = B + (size_t)(cbase + ra1) * D_EXP + c8;
    u16* lA0 = As + (size_t)(wave * 32) * 32;
    u16* lA1 = As + (size_t)(wave * 32 + 16) * 32;
    u16* lB0 = Bs + (size_t)(wave * 32) * 32;
    u16* lB1 = Bs + (size_t)(wave * 32 + 16) * 32;

    f32x4 acc[4][4];
    const f32x4 zero = {0.f, 0.f, 0.f, 0.f};
#pragma unroll
    for (int i = 0; i < 4; i++)
#pragma unroll
        for (int j = 0; j < 4; j++) acc[i][j] = zero;

    for (int k0 = 0; k0 < D_EXP; k0 += 32) {
        __syncthreads();
        gld_lds16(pa0 + k0, lA0);
        gld_lds16(pa1 + k0, lA1);
        gld_lds16(pb0 + k0, lB0);
        gld_lds16(pb1 + k0, lB1);
        __syncthreads();
        bf16x8 af[4];
#pragma unroll
        for (int sm = 0; sm < 4; sm++)
            af[sm] = *(const bf16x8*)&As[(wm * 64 + sm * 16 + ln) * 32 + quad * 8];
#pragma unroll
        for (int sn = 0; sn < 4; sn++) {
            const bf16x8 bfg = *(const bf16x8*)&Bs[(wn * 64 + sn * 16 + ln) * 32 + quad * 8];
#pragma unroll
            for (int sm = 0; sm < 4; sm++)
                acc[sm][sn] = __builtin_amdgcn_mfma_f32_16x16x32_bf16(af[sm], bfg, acc[sm][sn], 0, 0, 0);
        }
    }
#pragma unroll
    for (int sm = 0; sm < 4; sm++) {
#pragma unroll
        for (int r = 0; r < 4; r++) {
            int lrow = rb * 128 + wm * 64 + sm * 16 + quad * 4 + r;
            if (lrow >= L) continue;
            int tok = rows[s + lrow];
#pragma unroll
            for (int sn = 0; sn < 4; sn++) {
                int col = cbase + wn * 64 + sn * 16 + ln;
                atomicAdd(out + (size_t)tok * D_HID + col, acc[sm][sn][r]);
            }
        }
    }
}

// ---------------- launch ----------------
extern "C" void kernel_launch(void* const* d_in, const int* in_sizes, int n_in,
                              void* d_out, int out_size, void* d_ws, size_t ws_size,
                              hipStream_t stream) {
    const float* x       = (const float*)d_in[0];
    const float* W_g     = (const float*)d_in[1];
    const float* W_gate  = (const float*)d_in[2];
    const float* W_up    = (const float*)d_in[3];
    const float* W_down  = (const float*)d_in[4];
    const float* Ws_gate = (const float*)d_in[5];
    const float* Ws_up   = (const float*)d_in[6];
    const float* Ws_down = (const float*)d_in[7];
    float* out = (float*)d_out;
    char* ws = (char*)d_ws;

    u16*   xb    = (u16*)(ws + OFF_XB);
    u16*   Wg_t  = (u16*)(ws + OFF_WG);
    u16*   Wu_t  = (u16*)(ws + OFF_WU);
    u16*   Wd_t  = (u16*)(ws + OFF_WD);
    u16*   Wsg_t = (u16*)(ws + OFF_WSG);
    u16*   Wsu_t = (u16*)(ws + OFF_WSU);
    u16*   Wsd_t = (u16*)(ws + OFF_WSD);
    u16*   h     = (u16*)(ws + OFF_H);
    int*   rows  = (int*)(ws + OFF_ROWS);
    float* wslot = (float*)(ws + OFF_WSLOT);
    int*   seg   = (int*)(ws + OFF_SEG);
    int*   blkmap= (int*)(ws + OFF_BLK);
    int*   topi  = (int*)(ws + OFF_TOPI);
    float* topw  = (float*)(ws + OFF_TOPW);

    zero_out_kernel<<<dim3((N_TOK * D_HID) / (256 * 4)), dim3(256), 0, stream>>>(out);
    cvt_x_kernel<<<dim3((N_TOK * D_HID) / (256 * 8)), dim3(256), 0, stream>>>(x, xb);

    dim3 tb(32, 8);
    transpose_cvt_kernel<<<dim3(D_EXP / 32, D_HID / 32, NE), tb, 0, stream>>>(W_gate, Wg_t, D_HID, D_EXP);
    transpose_cvt_kernel<<<dim3(D_EXP / 32, D_HID / 32, NE), tb, 0, stream>>>(W_up, Wu_t, D_HID, D_EXP);
    transpose_cvt_kernel<<<dim3(D_HID / 32, D_EXP / 32, NE), tb, 0, stream>>>(W_down, Wd_t, D_EXP, D_HID);
    transpose_cvt_kernel<<<dim3(D_EXP / 32, D_HID / 32, 1), tb, 0, stream>>>(Ws_gate, Wsg_t, D_HID, D_EXP);
    transpose_cvt_kernel<<<dim3(D_EXP / 32, D_HID / 32, 1), tb, 0, stream>>>(Ws_up, Wsu_t, D_HID, D_EXP);
    transpose_cvt_kernel<<<dim3(D_HID / 32, D_EXP / 32, 1), tb, 0, stream>>>(Ws_down, Wsd_t, D_EXP, D_HID);

    router_kernel<<<dim3(N_TOK / 4), dim3(256), 0, stream>>>(x, W_g, topi, topw);
    builder_kernel<<<dim3(1), dim3(256), 0, stream>>>(topi, topw, rows, wslot, seg, blkmap);

    gemm1_kernel<<<dim3(MAX_BLK, D_EXP / 128), dim3(256), 0, stream>>>(
        xb, Wg_t, Wu_t, Wsg_t, Wsu_t, rows, wslot, seg, blkmap, h);
    gemm2_kernel<<<dim3(MAX_BLK, D_HID / 128), dim3(256), 0, stream>>>(
        h, Wd_t, Wsd_t, rows, seg, blkmap, out);
}

// Round 3
// 562.992 us; speedup vs baseline: 1.6372x; 1.1076x over previous
//
#include <hip/hip_runtime.h>
#include <cstdint>
#include <cstddef>

#define N_TOK 4096
#define D_HID 2048
#define D_EXP 1024
#define NE 8
#define N_ROUTED (N_TOK * 2)
#define N_ROWS (N_ROUTED + N_TOK)   // 12288: 8192 routed slots + 4096 shared
#define MAX_BLK 112                 // >= worst-case row-blocks (103)

typedef unsigned short u16;
typedef __bf16 bf16x8 __attribute__((ext_vector_type(8)));
typedef float f32x4 __attribute__((ext_vector_type(4)));

// ---------------- workspace layout (bytes) ----------------
constexpr size_t OFF_XB    = 0;                        // u16[N_TOK*D_HID]
constexpr size_t OFF_WG    = OFF_XB    + 16777216;     // u16[NE][D_EXP][D_HID]  (n,k)
constexpr size_t OFF_WU    = OFF_WG    + 33554432;     // u16[NE][D_EXP][D_HID]
constexpr size_t OFF_WD    = OFF_WU    + 33554432;     // u16[NE][D_HID][D_EXP]  (n,k)
constexpr size_t OFF_WSG   = OFF_WD    + 33554432;     // u16[D_EXP][D_HID]
constexpr size_t OFF_WSU   = OFF_WSG   + 4194304;      // u16[D_EXP][D_HID]
constexpr size_t OFF_WSD   = OFF_WSU   + 4194304;      // u16[D_HID][D_EXP]
constexpr size_t OFF_H     = OFF_WSD   + 4194304;      // u16[N_ROWS*D_EXP]
constexpr size_t OFF_ROWS  = OFF_H     + 25165824;     // int[N_ROWS]
constexpr size_t OFF_WSLOT = OFF_ROWS  + 49152;        // float[N_ROWS]
constexpr size_t OFF_SEG   = OFF_WSLOT + 49152;        // int[32]
constexpr size_t OFF_BLK   = OFF_SEG   + 128;          // int[192] block map
constexpr size_t OFF_TOPI  = OFF_BLK   + 768;          // int[2*N_TOK]
constexpr size_t OFF_TOPW  = OFF_TOPI  + 32768;        // float[2*N_TOK]
constexpr size_t OFF_INV   = OFF_TOPW  + 32768;        // int[2*N_TOK] token->slot
// h2 (u16[N_ROWS][D_HID] = 50.3 MB) ALIASES Wg_t/Wu_t (64 MB): those are dead
// after gemm1 completes, and gemm2/combine are stream-ordered after gemm1.
constexpr size_t OFF_H2    = OFF_WG;

__device__ __forceinline__ u16 f32_to_bf16(float f) {
    union { float f; unsigned int u; } c; c.f = f;
    unsigned int u = c.u;
    return (u16)((u + 0x7FFFu + ((u >> 16) & 1u)) >> 16);
}
__device__ __forceinline__ float bf16_to_f32(u16 v) {
    union { unsigned int u; float f; } c; c.u = ((unsigned int)v) << 16;
    return c.f;
}

// async global->LDS, 16B per lane; lds dest = wave-uniform base + lane*16
__device__ __forceinline__ void gld_lds16(const u16* g, u16* l) {
    __builtin_amdgcn_global_load_lds(
        (const __attribute__((address_space(1))) void*)g,
        (__attribute__((address_space(3))) void*)l,
        16, 0, 0);
}

// ---------------- x -> bf16 ----------------
__global__ void cvt_x_kernel(const float* __restrict__ x, u16* __restrict__ xb) {
    size_t i = ((size_t)blockIdx.x * 256 + threadIdx.x) * 8;
    float4 a = *(const float4*)(x + i);
    float4 b = *(const float4*)(x + i + 4);
    union { u16 us[8]; uint4 v; } r;
    r.us[0] = f32_to_bf16(a.x); r.us[1] = f32_to_bf16(a.y);
    r.us[2] = f32_to_bf16(a.z); r.us[3] = f32_to_bf16(a.w);
    r.us[4] = f32_to_bf16(b.x); r.us[5] = f32_to_bf16(b.y);
    r.us[6] = f32_to_bf16(b.z); r.us[7] = f32_to_bf16(b.w);
    *(uint4*)(xb + i) = r.v;
}

// ---------------- weight prep: fp32 [R][C] -> bf16 [C][R], batched ----------------
// gate/up family: R=2048 (k), C=1024 (n); 18 z-slices
__global__ void prep_gu_kernel(const float* __restrict__ Wg, const float* __restrict__ Wu,
                               const float* __restrict__ Wsg, const float* __restrict__ Wsu,
                               u16* __restrict__ Wg_t, u16* __restrict__ Wu_t,
                               u16* __restrict__ Wsg_t, u16* __restrict__ Wsu_t) {
    __shared__ float tile[64][66];   // pad 66: store-phase 8-lane k-groups 2-way max
    const int z = blockIdx.z;
    const float* src; u16* dst;
    if (z < 8)        { src = Wg + (size_t)z * (D_HID * D_EXP);       dst = Wg_t + (size_t)z * (D_HID * D_EXP); }
    else if (z < 16)  { src = Wu + (size_t)(z - 8) * (D_HID * D_EXP); dst = Wu_t + (size_t)(z - 8) * (D_HID * D_EXP); }
    else if (z == 16) { src = Wsg; dst = Wsg_t; }
    else              { src = Wsu; dst = Wsu_t; }
    const int c0 = blockIdx.x * 64, r0 = blockIdx.y * 64;
    const int tid = threadIdx.x;
    const int tx = tid & 15, ty = tid >> 4;
#pragma unroll
    for (int i = 0; i < 4; i++) {
        float4 v = *(const float4*)(src + (size_t)(r0 + ty + 16 * i) * D_EXP + c0 + tx * 4);
        tile[ty + 16 * i][tx * 4 + 0] = v.x;
        tile[ty + 16 * i][tx * 4 + 1] = v.y;
        tile[ty + 16 * i][tx * 4 + 2] = v.z;
        tile[ty + 16 * i][tx * 4 + 3] = v.w;
    }
    __syncthreads();
    const int kx = tid & 7, cy = tid >> 3;   // 8 k-groups x 32 n-rows
#pragma unroll
    for (int j = 0; j < 2; j++) {
        int n = cy + 32 * j;
        union { u16 us[8]; uint4 v; } r;
#pragma unroll
        for (int m = 0; m < 8; m++) r.us[m] = f32_to_bf16(tile[kx * 8 + m][n]);
        *(uint4*)(dst + (size_t)(c0 + n) * D_HID + r0 + kx * 8) = r.v;
    }
}

// down family: R=1024 (k), C=2048 (n); 9 z-slices
__global__ void prep_d_kernel(const float* __restrict__ Wd, const float* __restrict__ Wsd,
                              u16* __restrict__ Wd_t, u16* __restrict__ Wsd_t) {
    __shared__ float tile[64][66];
    const int z = blockIdx.z;
    const float* src; u16* dst;
    if (z < 8) { src = Wd + (size_t)z * (D_EXP * D_HID); dst = Wd_t + (size_t)z * (D_EXP * D_HID); }
    else       { src = Wsd; dst = Wsd_t; }
    const int c0 = blockIdx.x * 64, r0 = blockIdx.y * 64;
    const int tid = threadIdx.x;
    const int tx = tid & 15, ty = tid >> 4;
#pragma unroll
    for (int i = 0; i < 4; i++) {
        float4 v = *(const float4*)(src + (size_t)(r0 + ty + 16 * i) * D_HID + c0 + tx * 4);
        tile[ty + 16 * i][tx * 4 + 0] = v.x;
        tile[ty + 16 * i][tx * 4 + 1] = v.y;
        tile[ty + 16 * i][tx * 4 + 2] = v.z;
        tile[ty + 16 * i][tx * 4 + 3] = v.w;
    }
    __syncthreads();
    const int kx = tid & 7, cy = tid >> 3;
#pragma unroll
    for (int j = 0; j < 2; j++) {
        int n = cy + 32 * j;
        union { u16 us[8]; uint4 v; } r;
#pragma unroll
        for (int m = 0; m < 8; m++) r.us[m] = f32_to_bf16(tile[kx * 8 + m][n]);
        *(uint4*)(dst + (size_t)(c0 + n) * D_EXP + r0 + kx * 8) = r.v;
    }
}

// ---------------- router: softmax + top2 ----------------
__global__ void router_kernel(const float* __restrict__ x, const float* __restrict__ Wg,
                              int* __restrict__ topi, float* __restrict__ topw) {
    const int wave = threadIdx.x >> 6, lane = threadIdx.x & 63;
    const int t = blockIdx.x * 4 + wave;
    const float* xr = x + (size_t)t * D_HID;
    float acc[8] = {0.f, 0.f, 0.f, 0.f, 0.f, 0.f, 0.f, 0.f};
    for (int k = lane; k < D_HID; k += 64) {
        float xv = xr[k];
        float4 w0 = *(const float4*)(Wg + k * 8);
        float4 w1 = *(const float4*)(Wg + k * 8 + 4);
        acc[0] += xv * w0.x; acc[1] += xv * w0.y; acc[2] += xv * w0.z; acc[3] += xv * w0.w;
        acc[4] += xv * w1.x; acc[5] += xv * w1.y; acc[6] += xv * w1.z; acc[7] += xv * w1.w;
    }
#pragma unroll
    for (int e = 0; e < 8; e++)
#pragma unroll
        for (int off = 32; off > 0; off >>= 1)
            acc[e] += __shfl_xor(acc[e], off);
    if (lane == 0) {
        float mx = acc[0];
#pragma unroll
        for (int e = 1; e < 8; e++) mx = fmaxf(mx, acc[e]);
        float p[8], sum = 0.f;
#pragma unroll
        for (int e = 0; e < 8; e++) { p[e] = __expf(acc[e] - mx); sum += p[e]; }
        int i0 = 0; float b0 = p[0];
#pragma unroll
        for (int e = 1; e < 8; e++) if (p[e] > b0) { b0 = p[e]; i0 = e; }
        int i1 = -1; float b1 = -1.f;
#pragma unroll
        for (int e = 0; e < 8; e++) if (e != i0 && p[e] > b1) { b1 = p[e]; i1 = e; }
        float inv = 1.f / sum;
        topi[t * 2] = i0;  topi[t * 2 + 1] = i1;
        topw[t * 2] = b0 * inv; topw[t * 2 + 1] = b1 * inv;
    }
}

// ---------------- build expert segments + block map + inverse map ----------------
__global__ void builder_kernel(const int* __restrict__ topi, const float* __restrict__ topw,
                               int* __restrict__ rows, float* __restrict__ wslot,
                               int* __restrict__ seg, int* __restrict__ blkmap,
                               int* __restrict__ inv) {
    __shared__ int cnt[8], offs[8];
    const int tid = threadIdx.x;
    if (tid < 8) cnt[tid] = 0;
    __syncthreads();
    for (int i = tid; i < N_TOK * 2; i += 256) atomicAdd(&cnt[topi[i]], 1);
    __syncthreads();
    if (tid == 0) {
        int run = 0;
        for (int e = 0; e < 8; e++) {
            offs[e] = run; seg[e] = run; seg[16 + e] = cnt[e]; run += cnt[e];
        }
        seg[8] = N_ROUTED; seg[16 + 8] = N_TOK;
        int nb = 0;
        for (int e = 0; e < 9; e++) {
            int L = (e < 8) ? cnt[e] : N_TOK;
            for (int rb = 0; rb * 128 < L; rb++) blkmap[nb++] = (e << 8) | rb;
        }
        seg[10] = nb;
    }
    __syncthreads();
    for (int i = tid; i < N_TOK * 2; i += 256) {
        int e = topi[i];
        int p = atomicAdd(&offs[e], 1);
        rows[p] = i >> 1;
        wslot[p] = topw[i];
        inv[i] = p;
    }
    for (int t = tid; t < N_TOK; t += 256) {
        rows[N_ROUTED + t] = t;
        wslot[N_ROUTED + t] = 1.0f;
    }
}

// ---------------- GEMM1: gathered X @ {W_gate, W_up} + silu*up*w -> h (bf16) ----------------
__global__ __launch_bounds__(256, 2)
void gemm1_kernel(const u16* __restrict__ xb,
                  const u16* __restrict__ Wg_t, const u16* __restrict__ Wu_t,
                  const u16* __restrict__ Wsg_t, const u16* __restrict__ Wsu_t,
                  const int* __restrict__ rows, const float* __restrict__ wslot,
                  const int* __restrict__ seg, const int* __restrict__ blkmap,
                  u16* __restrict__ h) {
    if ((int)blockIdx.x >= seg[10]) return;
    const int code = blkmap[blockIdx.x];
    const int e = code >> 8, rb = code & 255;
    const int s = seg[e], L = seg[e + 16];
    const u16* Bg = (e < NE) ? Wg_t + (size_t)e * D_EXP * D_HID : Wsg_t;
    const u16* Bu = (e < NE) ? Wu_t + (size_t)e * D_EXP * D_HID : Wsu_t;
    const int cbase = blockIdx.y * 128;

    __shared__ u16 As[128 * 32];
    __shared__ u16 Bgs[128 * 32];
    __shared__ u16 Bus[128 * 32];
    __shared__ int tok_s[128];

    const int tid = threadIdx.x;
    if (tid < 128) {
        int lr = rb * 128 + tid;
        tok_s[tid] = rows[s + (lr < L ? lr : 0)];
    }
    __syncthreads();

    const int lane = tid & 63, wave = tid >> 6;
    const int wm = wave & 1, wn = wave >> 1;
    const int ln = lane & 15, quad = lane >> 4;

    const int lr16 = lane >> 2;
    const int c8 = (lane & 3) * 8;
    const int ra0 = wave * 32 + lr16, ra1 = ra0 + 16;
    const size_t ta0 = (size_t)tok_s[ra0] * D_HID + c8;
    const size_t ta1 = (size_t)tok_s[ra1] * D_HID + c8;
    const u16* pbg0 = Bg + (size_t)(cbase + ra0) * D_HID + c8;
    const u16* pbg1 = Bg + (size_t)(cbase + ra1) * D_HID + c8;
    const u16* pbu0 = Bu + (size_t)(cbase + ra0) * D_HID + c8;
    const u16* pbu1 = Bu + (size_t)(cbase + ra1) * D_HID + c8;
    u16* lA0 = As + (size_t)(wave * 32) * 32;
    u16* lA1 = As + (size_t)(wave * 32 + 16) * 32;
    u16* lG0 = Bgs + (size_t)(wave * 32) * 32;
    u16* lG1 = Bgs + (size_t)(wave * 32 + 16) * 32;
    u16* lU0 = Bus + (size_t)(wave * 32) * 32;
    u16* lU1 = Bus + (size_t)(wave * 32 + 16) * 32;

    f32x4 accg[4][4], accu[4][4];
    const f32x4 zero = {0.f, 0.f, 0.f, 0.f};
#pragma unroll
    for (int i = 0; i < 4; i++)
#pragma unroll
        for (int j = 0; j < 4; j++) { accg[i][j] = zero; accu[i][j] = zero; }

    for (int k0 = 0; k0 < D_HID; k0 += 32) {
        __syncthreads();
        gld_lds16(xb + ta0 + k0, lA0);
        gld_lds16(xb + ta1 + k0, lA1);
        gld_lds16(pbg0 + k0, lG0);
        gld_lds16(pbg1 + k0, lG1);
        gld_lds16(pbu0 + k0, lU0);
        gld_lds16(pbu1 + k0, lU1);
        __syncthreads();
        bf16x8 af[4];
#pragma unroll
        for (int sm = 0; sm < 4; sm++)
            af[sm] = *(const bf16x8*)&As[(wm * 64 + sm * 16 + ln) * 32 + quad * 8];
#pragma unroll
        for (int sn = 0; sn < 4; sn++) {
            const bf16x8 bgf = *(const bf16x8*)&Bgs[(wn * 64 + sn * 16 + ln) * 32 + quad * 8];
            const bf16x8 buf = *(const bf16x8*)&Bus[(wn * 64 + sn * 16 + ln) * 32 + quad * 8];
#pragma unroll
            for (int sm = 0; sm < 4; sm++) {
                accg[sm][sn] = __builtin_amdgcn_mfma_f32_16x16x32_bf16(af[sm], bgf, accg[sm][sn], 0, 0, 0);
                accu[sm][sn] = __builtin_amdgcn_mfma_f32_16x16x32_bf16(af[sm], buf, accu[sm][sn], 0, 0, 0);
            }
        }
    }
#pragma unroll
    for (int sm = 0; sm < 4; sm++) {
#pragma unroll
        for (int r = 0; r < 4; r++) {
            int lrow = rb * 128 + wm * 64 + sm * 16 + quad * 4 + r;
            if (lrow >= L) continue;
            int pos = s + lrow;
            float w = wslot[pos];
#pragma unroll
            for (int sn = 0; sn < 4; sn++) {
                float g = accg[sm][sn][r];
                float u = accu[sm][sn][r];
                float hv = (g / (1.f + __expf(-g))) * u * w;
                int col = cbase + wn * 64 + sn * 16 + ln;
                h[(size_t)pos * D_EXP + col] = f32_to_bf16(hv);
            }
        }
    }
}

// ---------------- GEMM2: h @ W_down -> h2 (bf16 per-slot, no atomics) ----------------
__global__ __launch_bounds__(256, 2)
void gemm2_kernel(const u16* __restrict__ h,
                  const u16* __restrict__ Wd_t, const u16* __restrict__ Wsd_t,
                  const int* __restrict__ seg, const int* __restrict__ blkmap,
                  u16* __restrict__ h2) {
    if ((int)blockIdx.x >= seg[10]) return;
    const int code = blkmap[blockIdx.x];
    const int e = code >> 8, rb = code & 255;
    const int s = seg[e], L = seg[e + 16];
    const u16* B = (e < NE) ? Wd_t + (size_t)e * D_HID * D_EXP : Wsd_t;  // [N=2048][K=1024]
    const int cbase = blockIdx.y * 128;

    __shared__ u16 As[128 * 32];
    __shared__ u16 Bs[128 * 32];

    const int tid = threadIdx.x;
    const int lane = tid & 63, wave = tid >> 6;
    const int wm = wave & 1, wn = wave >> 1;
    const int ln = lane & 15, quad = lane >> 4;

    const int lr16 = lane >> 2;
    const int c8 = (lane & 3) * 8;
    const int ra0 = wave * 32 + lr16, ra1 = ra0 + 16;
    const u16* pa0 = h + (size_t)(s + rb * 128 + ra0) * D_EXP + c8;
    const u16* pa1 = h + (size_t)(s + rb * 128 + ra1) * D_EXP + c8;
    const u16* pb0 = B + (size_t)(cbase + ra0) * D_EXP + c8;
    const u16* pb1 = B + (size_t)(cbase + ra1) * D_EXP + c8;
    u16* lA0 = As + (size_t)(wave * 32) * 32;
    u16* lA1 = As + (size_t)(wave * 32 + 16) * 32;
    u16* lB0 = Bs + (size_t)(wave * 32) * 32;
    u16* lB1 = Bs + (size_t)(wave * 32 + 16) * 32;

    f32x4 acc[4][4];
    const f32x4 zero = {0.f, 0.f, 0.f, 0.f};
#pragma unroll
    for (int i = 0; i < 4; i++)
#pragma unroll
        for (int j = 0; j < 4; j++) acc[i][j] = zero;

    for (int k0 = 0; k0 < D_EXP; k0 += 32) {
        __syncthreads();
        gld_lds16(pa0 + k0, lA0);
        gld_lds16(pa1 + k0, lA1);
        gld_lds16(pb0 + k0, lB0);
        gld_lds16(pb1 + k0, lB1);
        __syncthreads();
        bf16x8 af[4];
#pragma unroll
        for (int sm = 0; sm < 4; sm++)
            af[sm] = *(const bf16x8*)&As[(wm * 64 + sm * 16 + ln) * 32 + quad * 8];
#pragma unroll
        for (int sn = 0; sn < 4; sn++) {
            const bf16x8 bfg = *(const bf16x8*)&Bs[(wn * 64 + sn * 16 + ln) * 32 + quad * 8];
#pragma unroll
            for (int sm = 0; sm < 4; sm++)
                acc[sm][sn] = __builtin_amdgcn_mfma_f32_16x16x32_bf16(af[sm], bfg, acc[sm][sn], 0, 0, 0);
        }
    }
#pragma unroll
    for (int sm = 0; sm < 4; sm++) {
#pragma unroll
        for (int r = 0; r < 4; r++) {
            int lrow = rb * 128 + wm * 64 + sm * 16 + quad * 4 + r;
            if (lrow >= L) continue;
            size_t slot = (size_t)(s + lrow);
#pragma unroll
            for (int sn = 0; sn < 4; sn++) {
                int col = cbase + wn * 64 + sn * 16 + ln;
                h2[slot * D_HID + col] = f32_to_bf16(acc[sm][sn][r]);
            }
        }
    }
}

// ---------------- combine: out[t] = h2[slot0] + h2[slot1] + h2[shared] ----------------
__global__ void combine_kernel(const u16* __restrict__ h2, const int* __restrict__ inv,
                               float* __restrict__ out) {
    const int t = blockIdx.x;
    const int d = threadIdx.x * 8;
    const size_t r0 = (size_t)inv[t * 2] * D_HID + d;
    const size_t r1 = (size_t)inv[t * 2 + 1] * D_HID + d;
    const size_t r2 = (size_t)(N_ROUTED + t) * D_HID + d;
    union { uint4 v; u16 us[8]; } a, b, c;
    a.v = *(const uint4*)(h2 + r0);
    b.v = *(const uint4*)(h2 + r1);
    c.v = *(const uint4*)(h2 + r2);
    float4 lo, hi;
    lo.x = bf16_to_f32(a.us[0]) + bf16_to_f32(b.us[0]) + bf16_to_f32(c.us[0]);
    lo.y = bf16_to_f32(a.us[1]) + bf16_to_f32(b.us[1]) + bf16_to_f32(c.us[1]);
    lo.z = bf16_to_f32(a.us[2]) + bf16_to_f32(b.us[2]) + bf16_to_f32(c.us[2]);
    lo.w = bf16_to_f32(a.us[3]) + bf16_to_f32(b.us[3]) + bf16_to_f32(c.us[3]);
    hi.x = bf16_to_f32(a.us[4]) + bf16_to_f32(b.us[4]) + bf16_to_f32(c.us[4]);
    hi.y = bf16_to_f32(a.us[5]) + bf16_to_f32(b.us[5]) + bf16_to_f32(c.us[5]);
    hi.z = bf16_to_f32(a.us[6]) + bf16_to_f32(b.us[6]) + bf16_to_f32(c.us[6]);
    hi.w = bf16_to_f32(a.us[7]) + bf16_to_f32(b.us[7]) + bf16_to_f32(c.us[7]);
    float* o = out + (size_t)t * D_HID + d;
    *(float4*)o = lo;
    *(float4*)(o + 4) = hi;
}

// ---------------- launch ----------------
extern "C" void kernel_launch(void* const* d_in, const int* in_sizes, int n_in,
                              void* d_out, int out_size, void* d_ws, size_t ws_size,
                              hipStream_t stream) {
    const float* x       = (const float*)d_in[0];
    const float* W_g     = (const float*)d_in[1];
    const float* W_gate  = (const float*)d_in[2];
    const float* W_up    = (const float*)d_in[3];
    const float* W_down  = (const float*)d_in[4];
    const float* Ws_gate = (const float*)d_in[5];
    const float* Ws_up   = (const float*)d_in[6];
    const float* Ws_down = (const float*)d_in[7];
    float* out = (float*)d_out;
    char* ws = (char*)d_ws;

    u16*   xb    = (u16*)(ws + OFF_XB);
    u16*   Wg_t  = (u16*)(ws + OFF_WG);
    u16*   Wu_t  = (u16*)(ws + OFF_WU);
    u16*   Wd_t  = (u16*)(ws + OFF_WD);
    u16*   Wsg_t = (u16*)(ws + OFF_WSG);
    u16*   Wsu_t = (u16*)(ws + OFF_WSU);
    u16*   Wsd_t = (u16*)(ws + OFF_WSD);
    u16*   h     = (u16*)(ws + OFF_H);
    u16*   h2    = (u16*)(ws + OFF_H2);
    int*   rows  = (int*)(ws + OFF_ROWS);
    float* wslot = (float*)(ws + OFF_WSLOT);
    int*   seg   = (int*)(ws + OFF_SEG);
    int*   blkmap= (int*)(ws + OFF_BLK);
    int*   topi  = (int*)(ws + OFF_TOPI);
    float* topw  = (float*)(ws + OFF_TOPW);
    int*   inv   = (int*)(ws + OFF_INV);

    cvt_x_kernel<<<dim3((N_TOK * D_HID) / (256 * 8)), dim3(256), 0, stream>>>(x, xb);
    prep_gu_kernel<<<dim3(D_EXP / 64, D_HID / 64, 18), dim3(256), 0, stream>>>(
        W_gate, W_up, Ws_gate, Ws_up, Wg_t, Wu_t, Wsg_t, Wsu_t);
    prep_d_kernel<<<dim3(D_HID / 64, D_EXP / 64, 9), dim3(256), 0, stream>>>(
        W_down, Ws_down, Wd_t, Wsd_t);

    router_kernel<<<dim3(N_TOK / 4), dim3(256), 0, stream>>>(x, W_g, topi, topw);
    builder_kernel<<<dim3(1), dim3(256), 0, stream>>>(topi, topw, rows, wslot, seg, blkmap, inv);

    gemm1_kernel<<<dim3(MAX_BLK, D_EXP / 128), dim3(256), 0, stream>>>(
        xb, Wg_t, Wu_t, Wsg_t, Wsu_t, rows, wslot, seg, blkmap, h);
    gemm2_kernel<<<dim3(MAX_BLK, D_HID / 128), dim3(256), 0, stream>>>(
        h, Wd_t, Wsd_t, seg, blkmap, h2);
    combine_kernel<<<dim3(N_TOK), dim3(256), 0, stream>>>(h2, inv, out);
}